// Round 13
// baseline (325.702 us; speedup 1.0000x reference)
//
#include <hip/hip_runtime.h>
#include <hip/hip_bf16.h>

typedef __hip_bfloat16 bf16;
typedef _Float16 half2v __attribute__((ext_vector_type(2)));
typedef _Float16 half8  __attribute__((ext_vector_type(8)));
typedef float  float4v __attribute__((ext_vector_type(4)));
typedef unsigned uint4v __attribute__((ext_vector_type(4)));
typedef short  short8 __attribute__((ext_vector_type(8)));
typedef float  f32x4  __attribute__((ext_vector_type(4)));

// B=32, N=64, F_ATOM=82, F_PATH=102, H=8, DK=80, HIDDEN=256, DEPTH=3
// Inputs fp32, output fp32. hb = h*32 + b.

__device__ inline float bflo(unsigned w) { return __uint_as_float(w << 16); }
__device__ inline float bfhi(unsigned w) { return __uint_as_float(w & 0xFFFF0000u); }
__device__ inline unsigned pack2bf(float x, float y) {
    bf16 a = (bf16)x, c = (bf16)y;
    unsigned short ua = *(unsigned short*)&a, uc = *(unsigned short*)&c;
    return (unsigned)ua | ((unsigned)uc << 16);
}
__device__ inline unsigned pack2h(float x, float y) {
    _Float16 a = (_Float16)x, c = (_Float16)y;
    unsigned short ua = *(unsigned short*)&a, uc = *(unsigned short*)&c;
    return (unsigned)ua | ((unsigned)uc << 16);
}
__device__ inline half2v ash2(unsigned u) { return __builtin_bit_cast(half2v, u); }
__device__ inline unsigned asu2(half2v h) { return __builtin_bit_cast(unsigned, h); }

__device__ inline float fdot2acc(half2v a, half2v b, float s) {
#if __has_builtin(__builtin_amdgcn_fdot2)
    return __builtin_amdgcn_fdot2(a, b, s, false);
#else
    return s + (float)a.x * (float)b.x + (float)a.y * (float)b.y;
#endif
}

// ---------------------------------------------------------------------------
// Prep (grid-stride): WTg[2][80][128] bf16 (path), WTu[4][80][96] bf16 (uvam),
// WTa[8][80][96] bf16 (atom proj), WTo[256][736] fp16 (out proj), buvam[4][80].
// ---------------------------------------------------------------------------
__global__ __launch_bounds__(256) void prep_kernel(
    const float* __restrict__ W_atom_i, const float* __restrict__ W_attn_h,
    const float* __restrict__ b_attn_h, const float* __restrict__ W_msg_h,
    const float* __restrict__ W_atom_o,
    bf16* __restrict__ WTg, bf16* __restrict__ WTu, bf16* __restrict__ WTa,
    _Float16* __restrict__ WTo, float* __restrict__ buvam)
{
    int tid0 = blockIdx.x * 256 + threadIdx.x;
    int NT = gridDim.x * 256;
    for (int t = tid0; t < 2 * 80 * 128; t += NT) {
        int z = t / 10240, rem = t - z * 10240;
        int n = rem >> 7, k = rem & 127;
        const float* src = z ? W_msg_h : W_attn_h;
        WTg[t] = (bf16)((k < 102) ? src[(160 + k) * 80 + n] : 0.f);
    }
    for (int t = tid0; t < 4 * 80 * 96; t += NT) {
        int z = t / 7680, rem = t - z * 7680;
        int n = rem / 96, k = rem - n * 96;
        const float* src = (z < 2) ? W_attn_h : W_msg_h;
        WTu[t] = (bf16)((k < 80) ? src[((z & 1) * 80 + k) * 80 + n] : 0.f);
    }
    for (int t = tid0; t < 8 * 80 * 96; t += NT) {
        int h = t / 7680, rem = t - h * 7680;
        int n = rem / 96, k = rem - n * 96;
        WTa[t] = (bf16)((k < 82) ? W_atom_i[k * 640 + h * 80 + n] : 0.f);
    }
    for (int t = tid0; t < 256 * 736; t += NT) {
        int n = t / 736, f = t - n * 736;
        WTo[t] = (_Float16)((f < 722) ? W_atom_o[(size_t)f * 256 + n] : 0.f);
    }
    for (int t = tid0; t < 320; t += NT)
        buvam[t] = (t < 80) ? b_attn_h[t] : 0.f;
}

// ---------------------------------------------------------------------------
// Atom projection via MFMA. grid (32 rowtiles, 8 h) x 320 threads.
// ah0[(h*32+b)*64+i][n] = atom[b,i,:82] @ W_atom_i[:, h*80+n]
// A-tile [64][104] bf16 (pitch 104: 52 words, 2-way banks). K pad to 96.
// ---------------------------------------------------------------------------
__global__ __launch_bounds__(320) void atom_proj_mfma(
    const float* __restrict__ atom, const bf16* __restrict__ WTa,
    float* __restrict__ ah0)
{
    __shared__ bf16 Als[64 * 104];
    int t = threadIdx.x;
    int rowBase = blockIdx.x * 64;
    int h = blockIdx.y;
    int wave = t >> 6, lane = t & 63, ln = lane & 15, quad = lane >> 4;

    const short* Wp = (const short*)(WTa + (size_t)h * 80 * 96);
    short8 bfrag[3];
    #pragma unroll
    for (int kc = 0; kc < 3; kc++)
        bfrag[kc] = *(const short8*)(Wp + (wave * 16 + ln) * 96 + kc * 32 + quad * 8);

    size_t abase = (size_t)rowBase * 82;
    for (int e = t; e < 5248; e += 320) {
        int r = e / 82, c = e - r * 82;
        Als[r * 104 + c] = (bf16)atom[abase + e];
    }
    for (int e = t; e < 896; e += 320) {
        int r = e / 14, c = 82 + (e - r * 14);
        Als[r * 104 + c] = (bf16)0.f;
    }
    __syncthreads();

    const short* Ap = (const short*)Als;
    int nc = wave * 16 + ln;
    #pragma unroll
    for (int rt = 0; rt < 4; rt++) {
        f32x4 acc = (f32x4){0.f, 0.f, 0.f, 0.f};
        #pragma unroll
        for (int kc = 0; kc < 3; kc++) {
            short8 af = *(const short8*)(Ap + (rt * 16 + ln) * 104 + kc * 32 + quad * 8);
            acc = __builtin_amdgcn_mfma_f32_16x16x32_bf16(af, bfrag[kc], acc, 0, 0, 0);
        }
        #pragma unroll
        for (int r = 0; r < 4; r++) {
            int row = rowBase + rt * 16 + quad * 4 + r;
            int b = row >> 6, i = row & 63;
            ah0[(((size_t)(h * 32 + b)) * 64 + i) * 80 + nc] = acc[r];
        }
    }
}

// ---------------------------------------------------------------------------
// Path GEMM via MFMA; P2 fp16, PM3 bf16. (pitch 136 = 68 words ≡4 mod 32, ok)
// ---------------------------------------------------------------------------
__global__ __launch_bounds__(320) void path_gemm_mfma(
    const float* __restrict__ A,      // [131072][102]
    const bf16* __restrict__ WTg,     // [2][80][128]
    _Float16* __restrict__ P2h, bf16* __restrict__ PM3)
{
    __shared__ bf16 Als[64 * 136];

    int t = threadIdx.x;
    int bx = blockIdx.x;
    size_t abase = (size_t)bx * 6528;

    int wave = t >> 6, lane = t & 63;
    int ln = lane & 15, quad = lane >> 4;

    const short* Wp = (const short*)WTg;
    short8 bfrag[2][4];
    #pragma unroll
    for (int z = 0; z < 2; z++)
        #pragma unroll
        for (int kc = 0; kc < 4; kc++)
            bfrag[z][kc] = *(const short8*)(
                Wp + (size_t)(z * 80 + wave * 16 + ln) * 128 + kc * 32 + quad * 8);

    for (int e = t; e < 6528; e += 320) {
        int r = e / 102, c = e - r * 102;
        Als[r * 136 + c] = (bf16)A[abase + e];
    }
    for (int e = t; e < 2176; e += 320) {
        int r = e / 34, c = 102 + (e - r * 34);
        Als[r * 136 + c] = (bf16)0.f;
    }
    __syncthreads();

    const short* Ap = (const short*)Als;
    int nc = wave * 16 + ln;

    #pragma unroll
    for (int rt = 0; rt < 4; rt++) {
        f32x4 acc0 = (f32x4){0.f, 0.f, 0.f, 0.f};
        f32x4 acc1 = (f32x4){0.f, 0.f, 0.f, 0.f};
        #pragma unroll
        for (int kc = 0; kc < 4; kc++) {
            short8 af = *(const short8*)(
                Ap + (rt * 16 + ln) * 136 + kc * 32 + quad * 8);
            acc0 = __builtin_amdgcn_mfma_f32_16x16x32_bf16(af, bfrag[0][kc], acc0, 0, 0, 0);
            acc1 = __builtin_amdgcn_mfma_f32_16x16x32_bf16(af, bfrag[1][kc], acc1, 0, 0, 0);
        }
        #pragma unroll
        for (int r = 0; r < 4; r++) {
            int m = rt * 16 + quad * 4 + r;
            size_t row = (size_t)bx * 64 + m;
            P2h[row * 80 + nc] = (_Float16)acc0[r];
            PM3[row * 80 + nc] = (bf16)acc1[r];
        }
    }
}

// ---------------------------------------------------------------------------
// UVAM GEMM via MFMA. grid (hb=256, z=4) x 320 threads. A pitch 96->104
// (bank fix: 52 words ≡ 20 mod 32 -> 2-way instead of 8-way).
// ---------------------------------------------------------------------------
__global__ __launch_bounds__(320) void uvam_gemm_mfma(
    const float* __restrict__ A,        // [16384][80] current a_h
    const bf16* __restrict__ WTu,       // [4][80][96]
    const float* __restrict__ buvam,    // [4][80]
    unsigned* __restrict__ Ug, unsigned* __restrict__ Vg,
    unsigned* __restrict__ A1g, unsigned* __restrict__ AMg)
{
    __shared__ float Bounce[64 * 84];   // 21.5 KB; A-stage aliases front 13.3 KB
    bf16* Als = (bf16*)Bounce;          // [64][104]

    int t = threadIdx.x;
    int hb = blockIdx.x, z = blockIdx.y;
    int wave = t >> 6, lane = t & 63;
    int ln = lane & 15, quad = lane >> 4;

    const short* Wp = (const short*)(WTu + (size_t)z * 80 * 96);
    short8 bfrag[3];
    #pragma unroll
    for (int kc = 0; kc < 3; kc++)
        bfrag[kc] = *(const short8*)(Wp + (wave * 16 + ln) * 96 + kc * 32 + quad * 8);

    size_t abase = (size_t)hb * 64 * 80;
    for (int e = t; e < 5120; e += 320) {
        int r = e / 80, c = e - r * 80;
        Als[r * 104 + c] = (bf16)A[abase + e];
    }
    for (int e = t; e < 1024; e += 320) {
        int r = e >> 4, c = 80 + (e & 15);
        Als[r * 104 + c] = (bf16)0.f;
    }
    __syncthreads();

    const short* Ap = (const short*)Als;
    f32x4 acc[4];
    #pragma unroll
    for (int rt = 0; rt < 4; rt++) {
        acc[rt] = (f32x4){0.f, 0.f, 0.f, 0.f};
        #pragma unroll
        for (int kc = 0; kc < 3; kc++) {
            short8 af = *(const short8*)(Ap + (rt * 16 + ln) * 104 + kc * 32 + quad * 8);
            acc[rt] = __builtin_amdgcn_mfma_f32_16x16x32_bf16(af, bfrag[kc], acc[rt], 0, 0, 0);
        }
    }
    __syncthreads();                    // A-stage dead

    float bv = buvam[z * 80 + wave * 16 + ln];
    #pragma unroll
    for (int rt = 0; rt < 4; rt++)
        #pragma unroll
        for (int r = 0; r < 4; r++) {
            int m = rt * 16 + quad * 4 + r;
            Bounce[m * 84 + wave * 16 + ln] = acc[rt][r] + bv;
        }
    __syncthreads();

    unsigned* o = (z == 0) ? Ug : (z == 1) ? Vg : (z == 2) ? A1g : AMg;
    bool f16 = z < 2;
    size_t obase = (size_t)hb * 2560;
    for (int e = t; e < 2560; e += 320) {
        int j = e / 40, kp = e - j * 40;
        float x0 = Bounce[j * 84 + 2 * kp], x1 = Bounce[j * 84 + 2 * kp + 1];
        o[obase + e] = f16 ? pack2h(x0, x1) : pack2bf(x0, x1);
    }
}

// ---------------------------------------------------------------------------
// Fused attention layer v5 (R12 structure). launch_bounds (256,8): VGPR<=64,
// occupancy cap 100% (was 62.5% at min-waves 5).
// ---------------------------------------------------------------------------
__global__ __launch_bounds__(256, 8) void attn_layer_kernel(
    const unsigned* __restrict__ Ug,   // [256][64][40] fp16 pairs (U+b)
    const unsigned* __restrict__ Vg,   // [256][64][40] fp16 pairs
    const unsigned* __restrict__ A1g,  // [256][64][40] bf16 pairs
    const unsigned* __restrict__ AMg,  // [256][64][40] bf16 pairs
    const _Float16* __restrict__ P2h,  // [131072][80] fp16
    const bf16* __restrict__ PM3,      // [131072][80] bf16
    const float* __restrict__ mask,
    const float* __restrict__ w_attn_o, const float* __restrict__ b_attn_o,
    const float* __restrict__ b_msg_h,
    const float* __restrict__ ah0, float* __restrict__ ah_next)
{
    __shared__ unsigned VBu[64 * 41];
    __shared__ unsigned Uu[8 * 40];
    __shared__ unsigned A1u[8 * 40];
    __shared__ unsigned wo2[40];
    __shared__ float bm[80];
    __shared__ float PS[4][2][64];

    int x = blockIdx.x;
    int hb = x & 255, it = x >> 8;
    int b = hb & 31;
    int i0 = it * 8;
    int t = threadIdx.x;
    int wave = t >> 6, lane = t & 63;
    int iA = i0 + wave * 2;
    size_t gbase = (size_t)hb * 2560;

    // ---- prefetch P half-0 rows for both i (completed by barrier drain) ----
    const uint4v* prow0 = (const uint4v*)(P2h + ((size_t)(b * 64 + iA) * 64 + lane) * 80);
    const uint4v* prow1 = (const uint4v*)(P2h + ((size_t)(b * 64 + iA + 1) * 64 + lane) * 80);
    uint4v p0a[5], p1a[5];
    #pragma unroll
    for (int u = 0; u < 5; u++) { p0a[u] = prow0[u]; p1a[u] = prow1[u]; }

    // ---- staging ----
    for (int e = t; e < 2560; e += 256) {
        int j = e / 40, w = e - j * 40;
        VBu[j * 41 + w] = Vg[gbase + e];
    }
    for (int e = t; e < 320; e += 256) {
        int iq = e / 40, kp = e - iq * 40;
        Uu[e]  = Ug[gbase + (size_t)(i0 + iq) * 40 + kp];
        A1u[e] = A1g[gbase + (size_t)(i0 + iq) * 40 + kp];
    }
    if (t < 40) wo2[t] = pack2h(w_attn_o[2 * t], w_attn_o[2 * t + 1]);
    if (t < 80) bm[t] = b_msg_h[t];
    __syncthreads();

    float b0 = b_attn_o[0];
    int iq0 = wave * 2, iq1 = wave * 2 + 1;
    const half2v c06 = { (_Float16)0.6f, (_Float16)0.6f };
    const half2v c04 = { (_Float16)0.4f, (_Float16)0.4f };

    // ---- score: both i fused, lane = j ----
    float s0 = 0.f, s1 = 0.f;
    {
        const unsigned* pu0 = (const unsigned*)p0a;
        const unsigned* pu1 = (const unsigned*)p1a;
        #pragma unroll
        for (int kp = 0; kp < 20; kp++) {
            half2v v2 = ash2(VBu[lane * 41 + kp]);
            half2v w2 = ash2(wo2[kp]);
            half2v x0 = ash2(Uu[iq0 * 40 + kp]) + v2 + ash2(pu0[kp]);
            half2v a0 = ash2(asu2(x0) & 0x7FFF7FFFu);
            s0 = fdot2acc(x0 * c06 + a0 * c04, w2, s0);
            half2v x1 = ash2(Uu[iq1 * 40 + kp]) + v2 + ash2(pu1[kp]);
            half2v a1 = ash2(asu2(x1) & 0x7FFF7FFFu);
            s1 = fdot2acc(x1 * c06 + a1 * c04, w2, s1);
        }
    }
    {
        uint4v p0b[5], p1b[5];
        #pragma unroll
        for (int u = 0; u < 5; u++) { p0b[u] = prow0[5 + u]; p1b[u] = prow1[5 + u]; }
        const unsigned* pu0 = (const unsigned*)p0b;
        const unsigned* pu1 = (const unsigned*)p1b;
        #pragma unroll
        for (int kp = 0; kp < 20; kp++) {
            half2v v2 = ash2(VBu[lane * 41 + 20 + kp]);
            half2v w2 = ash2(wo2[20 + kp]);
            half2v x0 = ash2(Uu[iq0 * 40 + 20 + kp]) + v2 + ash2(pu0[kp]);
            half2v a0 = ash2(asu2(x0) & 0x7FFF7FFFu);
            s0 = fdot2acc(x0 * c06 + a0 * c04, w2, s0);
            half2v x1 = ash2(Uu[iq1 * 40 + 20 + kp]) + v2 + ash2(pu1[kp]);
            half2v a1 = ash2(asu2(x1) & 0x7FFF7FFFu);
            s1 = fdot2acc(x1 * c06 + a1 * c04, w2, s1);
        }
    }

    // ---- masked softmax per i (exact reference semantics) ----
    float sp[2];
    #pragma unroll
    for (int q = 0; q < 2; q++) {
        float s = q ? s1 : s0;
        float mj = mask[(size_t)b * 4096 + (size_t)(iA + q) * 64 + lane];
        float sc = (s + b0) * mj;
        float m = sc;
        #pragma unroll
        for (int off = 1; off < 64; off <<= 1) m = fmaxf(m, __shfl_xor(m, off, 64));
        float e = expf(sc - m) * mj;
        float d = e;
        #pragma unroll
        for (int off = 1; off < 64; off <<= 1) d += __shfl_xor(d, off, 64);
        float p = e / (d + 1e-20f) * mj;
        PS[wave][q][lane] = p;
        float spv = p;
        #pragma unroll
        for (int off = 1; off < 64; off <<= 1) spv += __shfl_xor(spv, off, 64);
        sp[q] = spv;
    }

    // ---- message: lanes 0..39 handle k-pairs; AM2 from global (L2-hot) ----
    if (lane < 40) {
        const unsigned* pm0 = (const unsigned*)(PM3 + ((size_t)(b * 64 + iA) * 64) * 80);
        const unsigned* pm1 = pm0 + 2560;
        const unsigned* amp = AMg + gbase;
        float a00 = 0.f, a01 = 0.f, a10 = 0.f, a11 = 0.f;
        #pragma unroll 8
        for (int j = 0; j < 64; j++) {
            unsigned u0 = pm0[j * 40 + lane];
            unsigned u1 = pm1[j * 40 + lane];
            unsigned aw = amp[j * 40 + lane];
            float am0 = bflo(aw), am1 = bfhi(aw);
            float p0 = PS[wave][0][j];
            float p1 = PS[wave][1][j];
            a00 += p0 * (bflo(u0) + am0);
            a01 += p0 * (bfhi(u0) + am1);
            a10 += p1 * (bflo(u1) + am0);
            a11 += p1 * (bfhi(u1) + am1);
        }

        int k0 = 2 * lane, k1 = 2 * lane + 1;
        #pragma unroll
        for (int q = 0; q < 2; q++) {
            int i = iA + q;
            int iq = wave * 2 + q;
            unsigned aw1 = A1u[iq * 40 + lane];
            size_t orow = ((size_t)hb * 64 + i) * 80;
            float mlo = (q == 0) ? a00 : a10;
            float mhi = (q == 0) ? a01 : a11;
            float pre0 = sp[q] * bflo(aw1) + mlo + bm[k0] + ah0[orow + k0];
            float pre1 = sp[q] * bfhi(aw1) + mhi + bm[k1] + ah0[orow + k1];
            ah_next[orow + k0] = pre0 > 0.f ? pre0 : 0.f;
            ah_next[orow + k1] = pre1 > 0.f ? pre1 : 0.f;
        }
    }
}

// ---------------------------------------------------------------------------
// Merge: X[row][f] = concat(atom, ah_merged) as fp16, pitch 736, pad zeroed.
// ---------------------------------------------------------------------------
__global__ __launch_bounds__(256) void merge_kernel(
    const float* __restrict__ atom, const float* __restrict__ ah,
    _Float16* __restrict__ X)
{
    int r0 = blockIdx.x * 8;
    int t = threadIdx.x;
    for (int e = t; e < 8 * 736; e += 256) {
        int r = e / 736, f = e - r * 736;
        int row = r0 + r;
        float v;
        if (f < 82) {
            v = atom[(size_t)row * 82 + f];
        } else if (f < 722) {
            int q = f - 82, h = q / 80, k = q - h * 80;
            int b = row >> 6, i = row & 63;
            v = ah[(((size_t)(h * 32 + b)) * 64 + i) * 80 + k];
        } else {
            v = 0.f;
        }
        X[(size_t)row * 736 + f] = (_Float16)v;
    }
}

// ---------------------------------------------------------------------------
// Out GEMM via f16 MFMA. grid (128 M-tiles of 16, 2 N-tiles of 128) x 256.
// Wave owns 32 cols (2 n-frags). A-tile [16][744] fp16 (pitch 744: 2-way).
// K = 736 = 23 chunks of 32; B-frags from WTo (L2-hot) per chunk.
// ---------------------------------------------------------------------------
__global__ __launch_bounds__(256) void out_gemm_mfma(
    const _Float16* __restrict__ X, const _Float16* __restrict__ WTo,
    const float* __restrict__ bo, float* __restrict__ out)
{
    __shared__ _Float16 Als[16 * 744];
    int bx = blockIdx.x, by = blockIdx.y;
    int t = threadIdx.x;
    int wave = t >> 6, lane = t & 63, ln = lane & 15, quad = lane >> 4;

    // stage A: 16 rows x 368 uints
    {
        const unsigned* src = (const unsigned*)(X + (size_t)bx * 16 * 736);
        for (int e = t; e < 16 * 368; e += 256) {
            int r = e / 368, u = e - r * 368;
            *(unsigned*)(Als + r * 744 + u * 2) = src[r * 368 + u];
        }
    }
    __syncthreads();

    int nbase = by * 128 + wave * 32;
    f32x4 acc0 = (f32x4){0.f, 0.f, 0.f, 0.f};
    f32x4 acc1 = (f32x4){0.f, 0.f, 0.f, 0.f};
    const _Float16* Bp0 = WTo + (size_t)(nbase + ln) * 736 + quad * 8;
    const _Float16* Bp1 = WTo + (size_t)(nbase + 16 + ln) * 736 + quad * 8;

    #pragma unroll
    for (int kc = 0; kc < 23; kc++) {
        half8 af = *(const half8*)(Als + ln * 744 + kc * 32 + quad * 8);
        half8 b0 = *(const half8*)(Bp0 + kc * 32);
        half8 b1 = *(const half8*)(Bp1 + kc * 32);
        acc0 = __builtin_amdgcn_mfma_f32_16x16x32_f16(af, b0, acc0, 0, 0, 0);
        acc1 = __builtin_amdgcn_mfma_f32_16x16x32_f16(af, b1, acc1, 0, 0, 0);
    }

    #pragma unroll
    for (int f = 0; f < 2; f++) {
        int c = nbase + f * 16 + ln;
        float bias = bo[c];
        f32x4 a = f ? acc1 : acc0;
        #pragma unroll
        for (int r = 0; r < 4; r++) {
            int m = quad * 4 + r;
            float v = a[r] + bias;
            out[(size_t)(bx * 16 + m) * 256 + c] = v > 0.f ? v : 0.f;
        }
    }
}

// ---------------------------------------------------------------------------
extern "C" void kernel_launch(void* const* d_in, const int* in_sizes, int n_in,
                              void* d_out, int out_size, void* d_ws, size_t ws_size,
                              hipStream_t stream)
{
    const float* atom_input = (const float*)d_in[0];
    const float* path_input = (const float*)d_in[1];
    const float* path_mask  = (const float*)d_in[2];
    const float* W_atom_i   = (const float*)d_in[3];
    const float* W_attn_h   = (const float*)d_in[4];
    const float* b_attn_h   = (const float*)d_in[5];
    const float* W_attn_o   = (const float*)d_in[6];
    const float* b_attn_o   = (const float*)d_in[7];
    const float* W_msg_h    = (const float*)d_in[8];
    const float* b_msg_h    = (const float*)d_in[9];
    const float* W_atom_o   = (const float*)d_in[10];
    const float* b_atom_o   = (const float*)d_in[11];
    float* out = (float*)d_out;

    // workspace carve-up (~67 MB)
    char* ws = (char*)d_ws;
    float*     ah0  = (float*)ws;     ws += (size_t)16384 * 80 * 4;
    float*     ah1  = (float*)ws;     ws += (size_t)16384 * 80 * 4;
    _Float16*  P2h  = (_Float16*)ws;  ws += (size_t)131072 * 80 * 2;
    bf16*      PM3  = (bf16*)ws;      ws += (size_t)131072 * 80 * 2;
    unsigned*  Ug   = (unsigned*)ws;  ws += (size_t)256 * 2560 * 4;
    unsigned*  Vg   = (unsigned*)ws;  ws += (size_t)256 * 2560 * 4;
    unsigned*  A1g  = (unsigned*)ws;  ws += (size_t)256 * 2560 * 4;
    unsigned*  AMg  = (unsigned*)ws;  ws += (size_t)256 * 2560 * 4;
    _Float16*  X    = (_Float16*)ws;  ws += (size_t)2048 * 736 * 2;
    bf16*      WTg  = (bf16*)ws;      ws += (size_t)2 * 80 * 128 * 2;
    bf16*      WTu  = (bf16*)ws;      ws += (size_t)4 * 80 * 96 * 2;
    bf16*      WTa  = (bf16*)ws;      ws += (size_t)8 * 80 * 96 * 2;
    _Float16*  WTo  = (_Float16*)ws;  ws += (size_t)256 * 736 * 2;
    float*     buvam= (float*)ws;     ws += (size_t)4 * 80 * 4;

    prep_kernel<<<256, 256, 0, stream>>>(W_atom_i, W_attn_h, b_attn_h, W_msg_h,
                                         W_atom_o, WTg, WTu, WTa, WTo, buvam);

    atom_proj_mfma<<<dim3(32, 8), 320, 0, stream>>>(atom_input, WTa, ah0);

    path_gemm_mfma<<<2048, 320, 0, stream>>>(path_input, WTg, P2h, PM3);

    const float* cur = ah0;
    float* nxt[2] = { ah1, ah1 };
    for (int layer = 0; layer < 2; layer++) {
        uvam_gemm_mfma<<<dim3(256, 4), 320, 0, stream>>>(
            cur, WTu, buvam, Ug, Vg, A1g, AMg);

        attn_layer_kernel<<<2048, 256, 0, stream>>>(
            Ug, Vg, A1g, AMg, P2h, PM3, path_mask, W_attn_o, b_attn_o, b_msg_h,
            ah0, nxt[layer]);
        cur = nxt[layer];
    }

    merge_kernel<<<256, 256, 0, stream>>>(atom_input, cur, X);
    out_gemm_mfma<<<dim3(128, 2), 256, 0, stream>>>(X, WTo, b_atom_o, out);
}

// Round 14
// 258.868 us; speedup vs baseline: 1.2582x; 1.2582x over previous
//
#include <hip/hip_runtime.h>
#include <hip/hip_bf16.h>

typedef __hip_bfloat16 bf16;
typedef _Float16 half2v __attribute__((ext_vector_type(2)));
typedef _Float16 half8  __attribute__((ext_vector_type(8)));
typedef float  float4v __attribute__((ext_vector_type(4)));
typedef unsigned uint4v __attribute__((ext_vector_type(4)));
typedef short  short8 __attribute__((ext_vector_type(8)));
typedef float  f32x4  __attribute__((ext_vector_type(4)));

// B=32, N=64, F_ATOM=82, F_PATH=102, H=8, DK=80, HIDDEN=256, DEPTH=3
// Inputs fp32, output fp32. hb = h*32 + b.

__device__ inline float bflo(unsigned w) { return __uint_as_float(w << 16); }
__device__ inline float bfhi(unsigned w) { return __uint_as_float(w & 0xFFFF0000u); }
__device__ inline unsigned pack2bf(float x, float y) {
    bf16 a = (bf16)x, c = (bf16)y;
    unsigned short ua = *(unsigned short*)&a, uc = *(unsigned short*)&c;
    return (unsigned)ua | ((unsigned)uc << 16);
}
__device__ inline unsigned pack2h(float x, float y) {
    _Float16 a = (_Float16)x, c = (_Float16)y;
    unsigned short ua = *(unsigned short*)&a, uc = *(unsigned short*)&c;
    return (unsigned)ua | ((unsigned)uc << 16);
}
__device__ inline half2v ash2(unsigned u) { return __builtin_bit_cast(half2v, u); }
__device__ inline unsigned asu2(half2v h) { return __builtin_bit_cast(unsigned, h); }

__device__ inline float fdot2acc(half2v a, half2v b, float s) {
#if __has_builtin(__builtin_amdgcn_fdot2)
    return __builtin_amdgcn_fdot2(a, b, s, false);
#else
    return s + (float)a.x * (float)b.x + (float)a.y * (float)b.y;
#endif
}

// ---------------------------------------------------------------------------
// Prep (grid-stride): WTg[2][80][128] bf16 (path), WTu[4][80][96] bf16 (uvam),
// WTa[8][80][96] bf16 (atom proj), WTo[256][736] fp16 (out proj), buvam[4][80].
// ---------------------------------------------------------------------------
__global__ __launch_bounds__(256) void prep_kernel(
    const float* __restrict__ W_atom_i, const float* __restrict__ W_attn_h,
    const float* __restrict__ b_attn_h, const float* __restrict__ W_msg_h,
    const float* __restrict__ W_atom_o,
    bf16* __restrict__ WTg, bf16* __restrict__ WTu, bf16* __restrict__ WTa,
    _Float16* __restrict__ WTo, float* __restrict__ buvam)
{
    int tid0 = blockIdx.x * 256 + threadIdx.x;
    int NT = gridDim.x * 256;
    for (int t = tid0; t < 2 * 80 * 128; t += NT) {
        int z = t / 10240, rem = t - z * 10240;
        int n = rem >> 7, k = rem & 127;
        const float* src = z ? W_msg_h : W_attn_h;
        WTg[t] = (bf16)((k < 102) ? src[(160 + k) * 80 + n] : 0.f);
    }
    for (int t = tid0; t < 4 * 80 * 96; t += NT) {
        int z = t / 7680, rem = t - z * 7680;
        int n = rem / 96, k = rem - n * 96;
        const float* src = (z < 2) ? W_attn_h : W_msg_h;
        WTu[t] = (bf16)((k < 80) ? src[((z & 1) * 80 + k) * 80 + n] : 0.f);
    }
    for (int t = tid0; t < 8 * 80 * 96; t += NT) {
        int h = t / 7680, rem = t - h * 7680;
        int n = rem / 96, k = rem - n * 96;
        WTa[t] = (bf16)((k < 82) ? W_atom_i[k * 640 + h * 80 + n] : 0.f);
    }
    for (int t = tid0; t < 256 * 736; t += NT) {
        int n = t / 736, f = t - n * 736;
        WTo[t] = (_Float16)((f < 722) ? W_atom_o[(size_t)f * 256 + n] : 0.f);
    }
    for (int t = tid0; t < 320; t += NT)
        buvam[t] = (t < 80) ? b_attn_h[t] : 0.f;
}

// ---------------------------------------------------------------------------
// Atom projection via MFMA. grid (32 rowtiles, 8 h) x 320 threads.
// ---------------------------------------------------------------------------
__global__ __launch_bounds__(320) void atom_proj_mfma(
    const float* __restrict__ atom, const bf16* __restrict__ WTa,
    float* __restrict__ ah0)
{
    __shared__ bf16 Als[64 * 104];
    int t = threadIdx.x;
    int rowBase = blockIdx.x * 64;
    int h = blockIdx.y;
    int wave = t >> 6, lane = t & 63, ln = lane & 15, quad = lane >> 4;

    const short* Wp = (const short*)(WTa + (size_t)h * 80 * 96);
    short8 bfrag[3];
    #pragma unroll
    for (int kc = 0; kc < 3; kc++)
        bfrag[kc] = *(const short8*)(Wp + (wave * 16 + ln) * 96 + kc * 32 + quad * 8);

    size_t abase = (size_t)rowBase * 82;
    for (int e = t; e < 5248; e += 320) {
        int r = e / 82, c = e - r * 82;
        Als[r * 104 + c] = (bf16)atom[abase + e];
    }
    for (int e = t; e < 896; e += 320) {
        int r = e / 14, c = 82 + (e - r * 14);
        Als[r * 104 + c] = (bf16)0.f;
    }
    __syncthreads();

    const short* Ap = (const short*)Als;
    int nc = wave * 16 + ln;
    #pragma unroll
    for (int rt = 0; rt < 4; rt++) {
        f32x4 acc = (f32x4){0.f, 0.f, 0.f, 0.f};
        #pragma unroll
        for (int kc = 0; kc < 3; kc++) {
            short8 af = *(const short8*)(Ap + (rt * 16 + ln) * 104 + kc * 32 + quad * 8);
            acc = __builtin_amdgcn_mfma_f32_16x16x32_bf16(af, bfrag[kc], acc, 0, 0, 0);
        }
        #pragma unroll
        for (int r = 0; r < 4; r++) {
            int row = rowBase + rt * 16 + quad * 4 + r;
            int b = row >> 6, i = row & 63;
            ah0[(((size_t)(h * 32 + b)) * 64 + i) * 80 + nc] = acc[r];
        }
    }
}

// ---------------------------------------------------------------------------
// Path GEMM via MFMA; P2 fp16, PM3 bf16.
// ---------------------------------------------------------------------------
__global__ __launch_bounds__(320) void path_gemm_mfma(
    const float* __restrict__ A,      // [131072][102]
    const bf16* __restrict__ WTg,     // [2][80][128]
    _Float16* __restrict__ P2h, bf16* __restrict__ PM3)
{
    __shared__ bf16 Als[64 * 136];

    int t = threadIdx.x;
    int bx = blockIdx.x;
    size_t abase = (size_t)bx * 6528;

    int wave = t >> 6, lane = t & 63;
    int ln = lane & 15, quad = lane >> 4;

    const short* Wp = (const short*)WTg;
    short8 bfrag[2][4];
    #pragma unroll
    for (int z = 0; z < 2; z++)
        #pragma unroll
        for (int kc = 0; kc < 4; kc++)
            bfrag[z][kc] = *(const short8*)(
                Wp + (size_t)(z * 80 + wave * 16 + ln) * 128 + kc * 32 + quad * 8);

    for (int e = t; e < 6528; e += 320) {
        int r = e / 102, c = e - r * 102;
        Als[r * 136 + c] = (bf16)A[abase + e];
    }
    for (int e = t; e < 2176; e += 320) {
        int r = e / 34, c = 102 + (e - r * 34);
        Als[r * 136 + c] = (bf16)0.f;
    }
    __syncthreads();

    const short* Ap = (const short*)Als;
    int nc = wave * 16 + ln;

    #pragma unroll
    for (int rt = 0; rt < 4; rt++) {
        f32x4 acc0 = (f32x4){0.f, 0.f, 0.f, 0.f};
        f32x4 acc1 = (f32x4){0.f, 0.f, 0.f, 0.f};
        #pragma unroll
        for (int kc = 0; kc < 4; kc++) {
            short8 af = *(const short8*)(
                Ap + (rt * 16 + ln) * 136 + kc * 32 + quad * 8);
            acc0 = __builtin_amdgcn_mfma_f32_16x16x32_bf16(af, bfrag[0][kc], acc0, 0, 0, 0);
            acc1 = __builtin_amdgcn_mfma_f32_16x16x32_bf16(af, bfrag[1][kc], acc1, 0, 0, 0);
        }
        #pragma unroll
        for (int r = 0; r < 4; r++) {
            int m = rt * 16 + quad * 4 + r;
            size_t row = (size_t)bx * 64 + m;
            P2h[row * 80 + nc] = (_Float16)acc0[r];
            PM3[row * 80 + nc] = (bf16)acc1[r];
        }
    }
}

// ---------------------------------------------------------------------------
// UVAM GEMM via MFMA. grid (hb=256, z=4) x 320 threads. A pitch 104.
// ---------------------------------------------------------------------------
__global__ __launch_bounds__(320) void uvam_gemm_mfma(
    const float* __restrict__ A,        // [16384][80] current a_h
    const bf16* __restrict__ WTu,       // [4][80][96]
    const float* __restrict__ buvam,    // [4][80]
    unsigned* __restrict__ Ug, unsigned* __restrict__ Vg,
    unsigned* __restrict__ A1g, unsigned* __restrict__ AMg)
{
    __shared__ float Bounce[64 * 84];   // 21.5 KB; A-stage aliases front 13.3 KB
    bf16* Als = (bf16*)Bounce;          // [64][104]

    int t = threadIdx.x;
    int hb = blockIdx.x, z = blockIdx.y;
    int wave = t >> 6, lane = t & 63;
    int ln = lane & 15, quad = lane >> 4;

    const short* Wp = (const short*)(WTu + (size_t)z * 80 * 96);
    short8 bfrag[3];
    #pragma unroll
    for (int kc = 0; kc < 3; kc++)
        bfrag[kc] = *(const short8*)(Wp + (wave * 16 + ln) * 96 + kc * 32 + quad * 8);

    size_t abase = (size_t)hb * 64 * 80;
    for (int e = t; e < 5120; e += 320) {
        int r = e / 80, c = e - r * 80;
        Als[r * 104 + c] = (bf16)A[abase + e];
    }
    for (int e = t; e < 1024; e += 320) {
        int r = e >> 4, c = 80 + (e & 15);
        Als[r * 104 + c] = (bf16)0.f;
    }
    __syncthreads();

    const short* Ap = (const short*)Als;
    f32x4 acc[4];
    #pragma unroll
    for (int rt = 0; rt < 4; rt++) {
        acc[rt] = (f32x4){0.f, 0.f, 0.f, 0.f};
        #pragma unroll
        for (int kc = 0; kc < 3; kc++) {
            short8 af = *(const short8*)(Ap + (rt * 16 + ln) * 104 + kc * 32 + quad * 8);
            acc[rt] = __builtin_amdgcn_mfma_f32_16x16x32_bf16(af, bfrag[kc], acc[rt], 0, 0, 0);
        }
    }
    __syncthreads();                    // A-stage dead

    float bv = buvam[z * 80 + wave * 16 + ln];
    #pragma unroll
    for (int rt = 0; rt < 4; rt++)
        #pragma unroll
        for (int r = 0; r < 4; r++) {
            int m = rt * 16 + quad * 4 + r;
            Bounce[m * 84 + wave * 16 + ln] = acc[rt][r] + bv;
        }
    __syncthreads();

    unsigned* o = (z == 0) ? Ug : (z == 1) ? Vg : (z == 2) ? A1g : AMg;
    bool f16 = z < 2;
    size_t obase = (size_t)hb * 2560;
    for (int e = t; e < 2560; e += 320) {
        int j = e / 40, kp = e - j * 40;
        float x0 = Bounce[j * 84 + 2 * kp], x1 = Bounce[j * 84 + 2 * kp + 1];
        o[obase + e] = f16 ? pack2h(x0, x1) : pack2bf(x0, x1);
    }
}

// ---------------------------------------------------------------------------
// Fused attention layer v5, R12 launch bounds (256,5): VGPR=48, NO spills.
// (R13's (256,8) forced VGPR=32 -> P-prefetch arrays spilled to scratch:
//  WRITE_SIZE 5->73 MB, dur 53->90 us. Occupancy is cheaper than spills.)
// ---------------------------------------------------------------------------
__global__ __launch_bounds__(256, 5) void attn_layer_kernel(
    const unsigned* __restrict__ Ug,   // [256][64][40] fp16 pairs (U+b)
    const unsigned* __restrict__ Vg,   // [256][64][40] fp16 pairs
    const unsigned* __restrict__ A1g,  // [256][64][40] bf16 pairs
    const unsigned* __restrict__ AMg,  // [256][64][40] bf16 pairs
    const _Float16* __restrict__ P2h,  // [131072][80] fp16
    const bf16* __restrict__ PM3,      // [131072][80] bf16
    const float* __restrict__ mask,
    const float* __restrict__ w_attn_o, const float* __restrict__ b_attn_o,
    const float* __restrict__ b_msg_h,
    const float* __restrict__ ah0, float* __restrict__ ah_next)
{
    __shared__ unsigned VBu[64 * 41];
    __shared__ unsigned Uu[8 * 40];
    __shared__ unsigned A1u[8 * 40];
    __shared__ unsigned wo2[40];
    __shared__ float bm[80];
    __shared__ float PS[4][2][64];

    int x = blockIdx.x;
    int hb = x & 255, it = x >> 8;
    int b = hb & 31;
    int i0 = it * 8;
    int t = threadIdx.x;
    int wave = t >> 6, lane = t & 63;
    int iA = i0 + wave * 2;
    size_t gbase = (size_t)hb * 2560;

    // ---- prefetch P half-0 rows for both i (completed by barrier drain) ----
    const uint4v* prow0 = (const uint4v*)(P2h + ((size_t)(b * 64 + iA) * 64 + lane) * 80);
    const uint4v* prow1 = (const uint4v*)(P2h + ((size_t)(b * 64 + iA + 1) * 64 + lane) * 80);
    uint4v p0a[5], p1a[5];
    #pragma unroll
    for (int u = 0; u < 5; u++) { p0a[u] = prow0[u]; p1a[u] = prow1[u]; }

    // ---- staging ----
    for (int e = t; e < 2560; e += 256) {
        int j = e / 40, w = e - j * 40;
        VBu[j * 41 + w] = Vg[gbase + e];
    }
    for (int e = t; e < 320; e += 256) {
        int iq = e / 40, kp = e - iq * 40;
        Uu[e]  = Ug[gbase + (size_t)(i0 + iq) * 40 + kp];
        A1u[e] = A1g[gbase + (size_t)(i0 + iq) * 40 + kp];
    }
    if (t < 40) wo2[t] = pack2h(w_attn_o[2 * t], w_attn_o[2 * t + 1]);
    if (t < 80) bm[t] = b_msg_h[t];
    __syncthreads();

    float b0 = b_attn_o[0];
    int iq0 = wave * 2, iq1 = wave * 2 + 1;
    const half2v c06 = { (_Float16)0.6f, (_Float16)0.6f };
    const half2v c04 = { (_Float16)0.4f, (_Float16)0.4f };

    // ---- score: both i fused, lane = j ----
    float s0 = 0.f, s1 = 0.f;
    {
        const unsigned* pu0 = (const unsigned*)p0a;
        const unsigned* pu1 = (const unsigned*)p1a;
        #pragma unroll
        for (int kp = 0; kp < 20; kp++) {
            half2v v2 = ash2(VBu[lane * 41 + kp]);
            half2v w2 = ash2(wo2[kp]);
            half2v x0 = ash2(Uu[iq0 * 40 + kp]) + v2 + ash2(pu0[kp]);
            half2v a0 = ash2(asu2(x0) & 0x7FFF7FFFu);
            s0 = fdot2acc(x0 * c06 + a0 * c04, w2, s0);
            half2v x1 = ash2(Uu[iq1 * 40 + kp]) + v2 + ash2(pu1[kp]);
            half2v a1 = ash2(asu2(x1) & 0x7FFF7FFFu);
            s1 = fdot2acc(x1 * c06 + a1 * c04, w2, s1);
        }
    }
    {
        uint4v p0b[5], p1b[5];
        #pragma unroll
        for (int u = 0; u < 5; u++) { p0b[u] = prow0[5 + u]; p1b[u] = prow1[5 + u]; }
        const unsigned* pu0 = (const unsigned*)p0b;
        const unsigned* pu1 = (const unsigned*)p1b;
        #pragma unroll
        for (int kp = 0; kp < 20; kp++) {
            half2v v2 = ash2(VBu[lane * 41 + 20 + kp]);
            half2v w2 = ash2(wo2[20 + kp]);
            half2v x0 = ash2(Uu[iq0 * 40 + 20 + kp]) + v2 + ash2(pu0[kp]);
            half2v a0 = ash2(asu2(x0) & 0x7FFF7FFFu);
            s0 = fdot2acc(x0 * c06 + a0 * c04, w2, s0);
            half2v x1 = ash2(Uu[iq1 * 40 + 20 + kp]) + v2 + ash2(pu1[kp]);
            half2v a1 = ash2(asu2(x1) & 0x7FFF7FFFu);
            s1 = fdot2acc(x1 * c06 + a1 * c04, w2, s1);
        }
    }

    // ---- masked softmax per i (exact reference semantics) ----
    float sp[2];
    #pragma unroll
    for (int q = 0; q < 2; q++) {
        float s = q ? s1 : s0;
        float mj = mask[(size_t)b * 4096 + (size_t)(iA + q) * 64 + lane];
        float sc = (s + b0) * mj;
        float m = sc;
        #pragma unroll
        for (int off = 1; off < 64; off <<= 1) m = fmaxf(m, __shfl_xor(m, off, 64));
        float e = expf(sc - m) * mj;
        float d = e;
        #pragma unroll
        for (int off = 1; off < 64; off <<= 1) d += __shfl_xor(d, off, 64);
        float p = e / (d + 1e-20f) * mj;
        PS[wave][q][lane] = p;
        float spv = p;
        #pragma unroll
        for (int off = 1; off < 64; off <<= 1) spv += __shfl_xor(spv, off, 64);
        sp[q] = spv;
    }

    // ---- message: lanes 0..39 handle k-pairs; AM2 from global (L2-hot) ----
    if (lane < 40) {
        const unsigned* pm0 = (const unsigned*)(PM3 + ((size_t)(b * 64 + iA) * 64) * 80);
        const unsigned* pm1 = pm0 + 2560;
        const unsigned* amp = AMg + gbase;
        float a00 = 0.f, a01 = 0.f, a10 = 0.f, a11 = 0.f;
        #pragma unroll 8
        for (int j = 0; j < 64; j++) {
            unsigned u0 = pm0[j * 40 + lane];
            unsigned u1 = pm1[j * 40 + lane];
            unsigned aw = amp[j * 40 + lane];
            float am0 = bflo(aw), am1 = bfhi(aw);
            float p0 = PS[wave][0][j];
            float p1 = PS[wave][1][j];
            a00 += p0 * (bflo(u0) + am0);
            a01 += p0 * (bfhi(u0) + am1);
            a10 += p1 * (bflo(u1) + am0);
            a11 += p1 * (bfhi(u1) + am1);
        }

        int k0 = 2 * lane, k1 = 2 * lane + 1;
        #pragma unroll
        for (int q = 0; q < 2; q++) {
            int i = iA + q;
            int iq = wave * 2 + q;
            unsigned aw1 = A1u[iq * 40 + lane];
            size_t orow = ((size_t)hb * 64 + i) * 80;
            float mlo = (q == 0) ? a00 : a10;
            float mhi = (q == 0) ? a01 : a11;
            float pre0 = sp[q] * bflo(aw1) + mlo + bm[k0] + ah0[orow + k0];
            float pre1 = sp[q] * bfhi(aw1) + mhi + bm[k1] + ah0[orow + k1];
            ah_next[orow + k0] = pre0 > 0.f ? pre0 : 0.f;
            ah_next[orow + k1] = pre1 > 0.f ? pre1 : 0.f;
        }
    }
}

// ---------------------------------------------------------------------------
// Merge: X[row][f] = concat(atom, ah_merged) as fp16, pitch 736, pad zeroed.
// ---------------------------------------------------------------------------
__global__ __launch_bounds__(256) void merge_kernel(
    const float* __restrict__ atom, const float* __restrict__ ah,
    _Float16* __restrict__ X)
{
    int r0 = blockIdx.x * 8;
    int t = threadIdx.x;
    for (int e = t; e < 8 * 736; e += 256) {
        int r = e / 736, f = e - r * 736;
        int row = r0 + r;
        float v;
        if (f < 82) {
            v = atom[(size_t)row * 82 + f];
        } else if (f < 722) {
            int q = f - 82, h = q / 80, k = q - h * 80;
            int b = row >> 6, i = row & 63;
            v = ah[(((size_t)(h * 32 + b)) * 64 + i) * 80 + k];
        } else {
            v = 0.f;
        }
        X[(size_t)row * 736 + f] = (_Float16)v;
    }
}

// ---------------------------------------------------------------------------
// Out GEMM via f16 MFMA. grid (128 M-tiles of 16, 2 N-tiles of 128) x 256.
// ---------------------------------------------------------------------------
__global__ __launch_bounds__(256) void out_gemm_mfma(
    const _Float16* __restrict__ X, const _Float16* __restrict__ WTo,
    const float* __restrict__ bo, float* __restrict__ out)
{
    __shared__ _Float16 Als[16 * 744];
    int bx = blockIdx.x, by = blockIdx.y;
    int t = threadIdx.x;
    int wave = t >> 6, lane = t & 63, ln = lane & 15, quad = lane >> 4;

    {
        const unsigned* src = (const unsigned*)(X + (size_t)bx * 16 * 736);
        for (int e = t; e < 16 * 368; e += 256) {
            int r = e / 368, u = e - r * 368;
            *(unsigned*)(Als + r * 744 + u * 2) = src[r * 368 + u];
        }
    }
    __syncthreads();

    int nbase = by * 128 + wave * 32;
    f32x4 acc0 = (f32x4){0.f, 0.f, 0.f, 0.f};
    f32x4 acc1 = (f32x4){0.f, 0.f, 0.f, 0.f};
    const _Float16* Bp0 = WTo + (size_t)(nbase + ln) * 736 + quad * 8;
    const _Float16* Bp1 = WTo + (size_t)(nbase + 16 + ln) * 736 + quad * 8;

    #pragma unroll
    for (int kc = 0; kc < 23; kc++) {
        half8 af = *(const half8*)(Als + ln * 744 + kc * 32 + quad * 8);
        half8 b0 = *(const half8*)(Bp0 + kc * 32);
        half8 b1 = *(const half8*)(Bp1 + kc * 32);
        acc0 = __builtin_amdgcn_mfma_f32_16x16x32_f16(af, b0, acc0, 0, 0, 0);
        acc1 = __builtin_amdgcn_mfma_f32_16x16x32_f16(af, b1, acc1, 0, 0, 0);
    }

    #pragma unroll
    for (int f = 0; f < 2; f++) {
        int c = nbase + f * 16 + ln;
        float bias = bo[c];
        f32x4 a = f ? acc1 : acc0;
        #pragma unroll
        for (int r = 0; r < 4; r++) {
            int m = quad * 4 + r;
            float v = a[r] + bias;
            out[(size_t)(bx * 16 + m) * 256 + c] = v > 0.f ? v : 0.f;
        }
    }
}

// ---------------------------------------------------------------------------
extern "C" void kernel_launch(void* const* d_in, const int* in_sizes, int n_in,
                              void* d_out, int out_size, void* d_ws, size_t ws_size,
                              hipStream_t stream)
{
    const float* atom_input = (const float*)d_in[0];
    const float* path_input = (const float*)d_in[1];
    const float* path_mask  = (const float*)d_in[2];
    const float* W_atom_i   = (const float*)d_in[3];
    const float* W_attn_h   = (const float*)d_in[4];
    const float* b_attn_h   = (const float*)d_in[5];
    const float* W_attn_o   = (const float*)d_in[6];
    const float* b_attn_o   = (const float*)d_in[7];
    const float* W_msg_h    = (const float*)d_in[8];
    const float* b_msg_h    = (const float*)d_in[9];
    const float* W_atom_o   = (const float*)d_in[10];
    const float* b_atom_o   = (const float*)d_in[11];
    float* out = (float*)d_out;

    // workspace carve-up (~67 MB)
    char* ws = (char*)d_ws;
    float*     ah0  = (float*)ws;     ws += (size_t)16384 * 80 * 4;
    float*     ah1  = (float*)ws;     ws += (size_t)16384 * 80 * 4;
    _Float16*  P2h  = (_Float16*)ws;  ws += (size_t)131072 * 80 * 2;
    bf16*      PM3  = (bf16*)ws;      ws += (size_t)131072 * 80 * 2;
    unsigned*  Ug   = (unsigned*)ws;  ws += (size_t)256 * 2560 * 4;
    unsigned*  Vg   = (unsigned*)ws;  ws += (size_t)256 * 2560 * 4;
    unsigned*  A1g  = (unsigned*)ws;  ws += (size_t)256 * 2560 * 4;
    unsigned*  AMg  = (unsigned*)ws;  ws += (size_t)256 * 2560 * 4;
    _Float16*  X    = (_Float16*)ws;  ws += (size_t)2048 * 736 * 2;
    bf16*      WTg  = (bf16*)ws;      ws += (size_t)2 * 80 * 128 * 2;
    bf16*      WTu  = (bf16*)ws;      ws += (size_t)4 * 80 * 96 * 2;
    bf16*      WTa  = (bf16*)ws;      ws += (size_t)8 * 80 * 96 * 2;
    _Float16*  WTo  = (_Float16*)ws;  ws += (size_t)256 * 736 * 2;
    float*     buvam= (float*)ws;     ws += (size_t)4 * 80 * 4;

    prep_kernel<<<256, 256, 0, stream>>>(W_atom_i, W_attn_h, b_attn_h, W_msg_h,
                                         W_atom_o, WTg, WTu, WTa, WTo, buvam);

    atom_proj_mfma<<<dim3(32, 8), 320, 0, stream>>>(atom_input, WTa, ah0);

    path_gemm_mfma<<<2048, 320, 0, stream>>>(path_input, WTg, P2h, PM3);

    const float* cur = ah0;
    float* nxt[2] = { ah1, ah1 };
    for (int layer = 0; layer < 2; layer++) {
        uvam_gemm_mfma<<<dim3(256, 4), 320, 0, stream>>>(
            cur, WTu, buvam, Ug, Vg, A1g, AMg);

        attn_layer_kernel<<<2048, 256, 0, stream>>>(
            Ug, Vg, A1g, AMg, P2h, PM3, path_mask, W_attn_o, b_attn_o, b_msg_h,
            ah0, nxt[layer]);
        cur = nxt[layer];
    }

    merge_kernel<<<256, 256, 0, stream>>>(atom_input, cur, X);
    out_gemm_mfma<<<dim3(128, 2), 256, 0, stream>>>(X, WTo, b_atom_o, out);
}

// Round 15
// 229.187 us; speedup vs baseline: 1.4211x; 1.1295x over previous
//
#include <hip/hip_runtime.h>
#include <hip/hip_bf16.h>

typedef __hip_bfloat16 bf16;
typedef _Float16 half2v __attribute__((ext_vector_type(2)));
typedef _Float16 half8  __attribute__((ext_vector_type(8)));
typedef float  float4v __attribute__((ext_vector_type(4)));
typedef unsigned uint4v __attribute__((ext_vector_type(4)));
typedef short  short8 __attribute__((ext_vector_type(8)));
typedef float  f32x4  __attribute__((ext_vector_type(4)));

// B=32, N=64, F_ATOM=82, F_PATH=102, H=8, DK=80, HIDDEN=256, DEPTH=3
// Inputs fp32, output fp32. hb = h*32 + b.

__device__ inline float bflo(unsigned w) { return __uint_as_float(w << 16); }
__device__ inline float bfhi(unsigned w) { return __uint_as_float(w & 0xFFFF0000u); }
__device__ inline unsigned pack2bf(float x, float y) {
    bf16 a = (bf16)x, c = (bf16)y;
    unsigned short ua = *(unsigned short*)&a, uc = *(unsigned short*)&c;
    return (unsigned)ua | ((unsigned)uc << 16);
}
__device__ inline unsigned pack2h(float x, float y) {
    _Float16 a = (_Float16)x, c = (_Float16)y;
    unsigned short ua = *(unsigned short*)&a, uc = *(unsigned short*)&c;
    return (unsigned)ua | ((unsigned)uc << 16);
}
__device__ inline half2v ash2(unsigned u) { return __builtin_bit_cast(half2v, u); }
__device__ inline unsigned asu2(half2v h) { return __builtin_bit_cast(unsigned, h); }

__device__ inline float fdot2acc(half2v a, half2v b, float s) {
#if __has_builtin(__builtin_amdgcn_fdot2)
    return __builtin_amdgcn_fdot2(a, b, s, false);
#else
    return s + (float)a.x * (float)b.x + (float)a.y * (float)b.y;
#endif
}

// ---------------------------------------------------------------------------
// Prep (grid-stride): WTg[2][80][128] bf16 (path), WTu[4][80][96] bf16 (uvam),
// WTa[8][80][96] bf16 (atom proj), WTo[256][736] fp16 (out proj), buvam[4][80].
// ---------------------------------------------------------------------------
__global__ __launch_bounds__(256) void prep_kernel(
    const float* __restrict__ W_atom_i, const float* __restrict__ W_attn_h,
    const float* __restrict__ b_attn_h, const float* __restrict__ W_msg_h,
    const float* __restrict__ W_atom_o,
    bf16* __restrict__ WTg, bf16* __restrict__ WTu, bf16* __restrict__ WTa,
    _Float16* __restrict__ WTo, float* __restrict__ buvam)
{
    int tid0 = blockIdx.x * 256 + threadIdx.x;
    int NT = gridDim.x * 256;
    for (int t = tid0; t < 2 * 80 * 128; t += NT) {
        int z = t / 10240, rem = t - z * 10240;
        int n = rem >> 7, k = rem & 127;
        const float* src = z ? W_msg_h : W_attn_h;
        WTg[t] = (bf16)((k < 102) ? src[(160 + k) * 80 + n] : 0.f);
    }
    for (int t = tid0; t < 4 * 80 * 96; t += NT) {
        int z = t / 7680, rem = t - z * 7680;
        int n = rem / 96, k = rem - n * 96;
        const float* src = (z < 2) ? W_attn_h : W_msg_h;
        WTu[t] = (bf16)((k < 80) ? src[((z & 1) * 80 + k) * 80 + n] : 0.f);
    }
    for (int t = tid0; t < 8 * 80 * 96; t += NT) {
        int h = t / 7680, rem = t - h * 7680;
        int n = rem / 96, k = rem - n * 96;
        WTa[t] = (bf16)((k < 82) ? W_atom_i[k * 640 + h * 80 + n] : 0.f);
    }
    for (int t = tid0; t < 256 * 736; t += NT) {
        int n = t / 736, f = t - n * 736;
        WTo[t] = (_Float16)((f < 722) ? W_atom_o[(size_t)f * 256 + n] : 0.f);
    }
    for (int t = tid0; t < 320; t += NT)
        buvam[t] = (t < 80) ? b_attn_h[t] : 0.f;
}

// ---------------------------------------------------------------------------
// Atom projection via MFMA. grid (32 rowtiles, 8 h) x 320 threads.
// ---------------------------------------------------------------------------
__global__ __launch_bounds__(320) void atom_proj_mfma(
    const float* __restrict__ atom, const bf16* __restrict__ WTa,
    float* __restrict__ ah0)
{
    __shared__ bf16 Als[64 * 104];
    int t = threadIdx.x;
    int rowBase = blockIdx.x * 64;
    int h = blockIdx.y;
    int wave = t >> 6, lane = t & 63, ln = lane & 15, quad = lane >> 4;

    const short* Wp = (const short*)(WTa + (size_t)h * 80 * 96);
    short8 bfrag[3];
    #pragma unroll
    for (int kc = 0; kc < 3; kc++)
        bfrag[kc] = *(const short8*)(Wp + (wave * 16 + ln) * 96 + kc * 32 + quad * 8);

    // float4-vectorized staging (5248 floats = 1312 float4; rows may split)
    {
        const float4v* A4 = (const float4v*)(atom + (size_t)rowBase * 82);
        for (int e4 = t; e4 < 1312; e4 += 320) {
            float4v v = A4[e4];
            int idx = e4 * 4;
            #pragma unroll
            for (int q = 0; q < 4; q++) {
                int ii = idx + q;
                int r = ii / 82, c = ii - r * 82;
                Als[r * 104 + c] = (bf16)v[q];
            }
        }
    }
    for (int e = t; e < 896; e += 320) {
        int r = e / 14, c = 82 + (e - r * 14);
        Als[r * 104 + c] = (bf16)0.f;
    }
    __syncthreads();

    const short* Ap = (const short*)Als;
    int nc = wave * 16 + ln;
    #pragma unroll
    for (int rt = 0; rt < 4; rt++) {
        f32x4 acc = (f32x4){0.f, 0.f, 0.f, 0.f};
        #pragma unroll
        for (int kc = 0; kc < 3; kc++) {
            short8 af = *(const short8*)(Ap + (rt * 16 + ln) * 104 + kc * 32 + quad * 8);
            acc = __builtin_amdgcn_mfma_f32_16x16x32_bf16(af, bfrag[kc], acc, 0, 0, 0);
        }
        #pragma unroll
        for (int r = 0; r < 4; r++) {
            int row = rowBase + rt * 16 + quad * 4 + r;
            int b = row >> 6, i = row & 63;
            ah0[(((size_t)(h * 32 + b)) * 64 + i) * 80 + nc] = acc[r];
        }
    }
}

// ---------------------------------------------------------------------------
// Path GEMM via MFMA. Outputs:
//   PT4[(b,i)][g=10][j=64] uint4 (fp16 pairs, k=8g..8g+7 of column j)
//     -> attn score reads are fully coalesced (16B/lane contiguous in j)
//   PM3[(b,i,j)][k] bf16 row-major (message reads already coalesced per j)
// ---------------------------------------------------------------------------
__global__ __launch_bounds__(320) void path_gemm_mfma(
    const float* __restrict__ A,      // [131072][102]
    const bf16* __restrict__ WTg,     // [2][80][128]
    uint4v* __restrict__ PT4, bf16* __restrict__ PM3)
{
    __shared__ bf16 Als[64 * 136];    // A stage; epilogue: fp16 Cb[64][84]

    int t = threadIdx.x;
    int bx = blockIdx.x;

    int wave = t >> 6, lane = t & 63;
    int ln = lane & 15, quad = lane >> 4;

    const short* Wp = (const short*)WTg;
    short8 bfrag[2][4];
    #pragma unroll
    for (int z = 0; z < 2; z++)
        #pragma unroll
        for (int kc = 0; kc < 4; kc++)
            bfrag[z][kc] = *(const short8*)(
                Wp + (size_t)(z * 80 + wave * 16 + ln) * 128 + kc * 32 + quad * 8);

    // float4-vectorized staging (6528 floats = 1632 float4)
    {
        const float4v* A4 = (const float4v*)(A + (size_t)bx * 6528);
        for (int e4 = t; e4 < 1632; e4 += 320) {
            float4v v = A4[e4];
            int idx = e4 * 4;
            #pragma unroll
            for (int q = 0; q < 4; q++) {
                int ii = idx + q;
                int r = ii / 102, c = ii - r * 102;
                Als[r * 136 + c] = (bf16)v[q];
            }
        }
    }
    for (int e = t; e < 2176; e += 320) {
        int r = e / 34, c = 102 + (e - r * 34);
        Als[r * 136 + c] = (bf16)0.f;
    }
    __syncthreads();

    const short* Ap = (const short*)Als;
    int nc = wave * 16 + ln;

    f32x4 acc0[4], acc1[4];
    #pragma unroll
    for (int rt = 0; rt < 4; rt++) {
        acc0[rt] = (f32x4){0.f, 0.f, 0.f, 0.f};
        acc1[rt] = (f32x4){0.f, 0.f, 0.f, 0.f};
        #pragma unroll
        for (int kc = 0; kc < 4; kc++) {
            short8 af = *(const short8*)(
                Ap + (rt * 16 + ln) * 136 + kc * 32 + quad * 8);
            acc0[rt] = __builtin_amdgcn_mfma_f32_16x16x32_bf16(af, bfrag[0][kc], acc0[rt], 0, 0, 0);
            acc1[rt] = __builtin_amdgcn_mfma_f32_16x16x32_bf16(af, bfrag[1][kc], acc1[rt], 0, 0, 0);
        }
    }

    // PM3 direct stores (no LDS) before the barrier
    #pragma unroll
    for (int rt = 0; rt < 4; rt++)
        #pragma unroll
        for (int r = 0; r < 4; r++) {
            int m = rt * 16 + quad * 4 + r;
            PM3[(size_t)bx * 5120 + m * 80 + nc] = (bf16)acc1[rt][r];
        }

    __syncthreads();                  // all MFMA reads of Als done
    _Float16* Cb = (_Float16*)Als;    // [64][84] fp16 bounce for P
    #pragma unroll
    for (int rt = 0; rt < 4; rt++)
        #pragma unroll
        for (int r = 0; r < 4; r++) {
            int m = rt * 16 + quad * 4 + r;
            Cb[m * 84 + nc] = (_Float16)acc0[rt][r];
        }
    __syncthreads();

    // pack PT4: uint4 per (g,j) = k 8g..8g+7 of column j; coalesced stores
    uint4v* dst = PT4 + (size_t)bx * 640;
    for (int e = t; e < 640; e += 320) {
        int g = e >> 6, j = e & 63;
        const unsigned* src = (const unsigned*)(Cb + j * 84 + g * 8);
        uint4v v = { src[0], src[1], src[2], src[3] };
        dst[(size_t)g * 64 + j] = v;
    }
}

// ---------------------------------------------------------------------------
// UVAM GEMM via MFMA. grid (hb=256, z=4) x 320 threads. A pitch 104.
// ---------------------------------------------------------------------------
__global__ __launch_bounds__(320) void uvam_gemm_mfma(
    const float* __restrict__ A,        // [16384][80] current a_h
    const bf16* __restrict__ WTu,       // [4][80][96]
    const float* __restrict__ buvam,    // [4][80]
    unsigned* __restrict__ Ug, unsigned* __restrict__ Vg,
    unsigned* __restrict__ A1g, unsigned* __restrict__ AMg)
{
    __shared__ float Bounce[64 * 84];   // 21.5 KB; A-stage aliases front 13.3 KB
    bf16* Als = (bf16*)Bounce;          // [64][104]

    int t = threadIdx.x;
    int hb = blockIdx.x, z = blockIdx.y;
    int wave = t >> 6, lane = t & 63;
    int ln = lane & 15, quad = lane >> 4;

    const short* Wp = (const short*)(WTu + (size_t)z * 80 * 96);
    short8 bfrag[3];
    #pragma unroll
    for (int kc = 0; kc < 3; kc++)
        bfrag[kc] = *(const short8*)(Wp + (wave * 16 + ln) * 96 + kc * 32 + quad * 8);

    // float4-vectorized staging (5120 floats = 1280 float4, 80%4==0: no row split)
    {
        const float4v* A4 = (const float4v*)(A + (size_t)hb * 5120);
        for (int e4 = t; e4 < 1280; e4 += 320) {
            float4v v = A4[e4];
            int idx = e4 * 4;
            int r = idx / 80, c = idx - r * 80;
            #pragma unroll
            for (int q = 0; q < 4; q++)
                Als[r * 104 + c + q] = (bf16)v[q];
        }
    }
    for (int e = t; e < 1024; e += 320) {
        int r = e >> 4, c = 80 + (e & 15);
        Als[r * 104 + c] = (bf16)0.f;
    }
    __syncthreads();

    const short* Ap = (const short*)Als;
    f32x4 acc[4];
    #pragma unroll
    for (int rt = 0; rt < 4; rt++) {
        acc[rt] = (f32x4){0.f, 0.f, 0.f, 0.f};
        #pragma unroll
        for (int kc = 0; kc < 3; kc++) {
            short8 af = *(const short8*)(Ap + (rt * 16 + ln) * 104 + kc * 32 + quad * 8);
            acc[rt] = __builtin_amdgcn_mfma_f32_16x16x32_bf16(af, bfrag[kc], acc[rt], 0, 0, 0);
        }
    }
    __syncthreads();                    // A-stage dead

    float bv = buvam[z * 80 + wave * 16 + ln];
    #pragma unroll
    for (int rt = 0; rt < 4; rt++)
        #pragma unroll
        for (int r = 0; r < 4; r++) {
            int m = rt * 16 + quad * 4 + r;
            Bounce[m * 84 + wave * 16 + ln] = acc[rt][r] + bv;
        }
    __syncthreads();

    unsigned* o = (z == 0) ? Ug : (z == 1) ? Vg : (z == 2) ? A1g : AMg;
    bool f16 = z < 2;
    size_t obase = (size_t)hb * 2560;
    for (int e = t; e < 2560; e += 320) {
        int j = e / 40, kp = e - j * 40;
        float x0 = Bounce[j * 84 + 2 * kp], x1 = Bounce[j * 84 + 2 * kp + 1];
        o[obase + e] = f16 ? pack2h(x0, x1) : pack2bf(x0, x1);
    }
}

// ---------------------------------------------------------------------------
// Fused attention layer v6: (256,5) — VGPR=48, no spills (R13 lesson).
// Score reads PT4 layout: fully coalesced 16B/lane loads, register contents
// identical to the old row-major uint4 reads.
// ---------------------------------------------------------------------------
__global__ __launch_bounds__(256, 5) void attn_layer_kernel(
    const unsigned* __restrict__ Ug,   // [256][64][40] fp16 pairs (U+b)
    const unsigned* __restrict__ Vg,   // [256][64][40] fp16 pairs
    const unsigned* __restrict__ A1g,  // [256][64][40] bf16 pairs
    const unsigned* __restrict__ AMg,  // [256][64][40] bf16 pairs
    const uint4v* __restrict__ PT4,    // [(b,i)][10][64] uint4 fp16-pairs
    const bf16* __restrict__ PM3,      // [131072][80] bf16
    const float* __restrict__ mask,
    const float* __restrict__ w_attn_o, const float* __restrict__ b_attn_o,
    const float* __restrict__ b_msg_h,
    const float* __restrict__ ah0, float* __restrict__ ah_next)
{
    __shared__ unsigned VBu[64 * 41];
    __shared__ unsigned Uu[8 * 40];
    __shared__ unsigned A1u[8 * 40];
    __shared__ unsigned wo2[40];
    __shared__ float bm[80];
    __shared__ float PS[4][2][64];

    int x = blockIdx.x;
    int hb = x & 255, it = x >> 8;
    int b = hb & 31;
    int i0 = it * 8;
    int t = threadIdx.x;
    int wave = t >> 6, lane = t & 63;
    int iA = i0 + wave * 2;
    size_t gbase = (size_t)hb * 2560;

    // ---- prefetch P half-0 for both i (coalesced; completed by barrier) ----
    const uint4v* prow0 = PT4 + (size_t)(b * 64 + iA) * 640 + lane;
    const uint4v* prow1 = prow0 + 640;
    uint4v p0a[5], p1a[5];
    #pragma unroll
    for (int u = 0; u < 5; u++) { p0a[u] = prow0[u * 64]; p1a[u] = prow1[u * 64]; }

    // ---- staging ----
    for (int e = t; e < 2560; e += 256) {
        int j = e / 40, w = e - j * 40;
        VBu[j * 41 + w] = Vg[gbase + e];
    }
    for (int e = t; e < 320; e += 256) {
        int iq = e / 40, kp = e - iq * 40;
        Uu[e]  = Ug[gbase + (size_t)(i0 + iq) * 40 + kp];
        A1u[e] = A1g[gbase + (size_t)(i0 + iq) * 40 + kp];
    }
    if (t < 40) wo2[t] = pack2h(w_attn_o[2 * t], w_attn_o[2 * t + 1]);
    if (t < 80) bm[t] = b_msg_h[t];
    __syncthreads();

    float b0 = b_attn_o[0];
    int iq0 = wave * 2, iq1 = wave * 2 + 1;
    const half2v c06 = { (_Float16)0.6f, (_Float16)0.6f };
    const half2v c04 = { (_Float16)0.4f, (_Float16)0.4f };

    // ---- score: both i fused, lane = j ----
    float s0 = 0.f, s1 = 0.f;
    {
        const unsigned* pu0 = (const unsigned*)p0a;
        const unsigned* pu1 = (const unsigned*)p1a;
        #pragma unroll
        for (int kp = 0; kp < 20; kp++) {
            half2v v2 = ash2(VBu[lane * 41 + kp]);
            half2v w2 = ash2(wo2[kp]);
            half2v x0 = ash2(Uu[iq0 * 40 + kp]) + v2 + ash2(pu0[kp]);
            half2v a0 = ash2(asu2(x0) & 0x7FFF7FFFu);
            s0 = fdot2acc(x0 * c06 + a0 * c04, w2, s0);
            half2v x1 = ash2(Uu[iq1 * 40 + kp]) + v2 + ash2(pu1[kp]);
            half2v a1 = ash2(asu2(x1) & 0x7FFF7FFFu);
            s1 = fdot2acc(x1 * c06 + a1 * c04, w2, s1);
        }
    }
    {
        uint4v p0b[5], p1b[5];
        #pragma unroll
        for (int u = 0; u < 5; u++) {
            p0b[u] = prow0[(5 + u) * 64];
            p1b[u] = prow1[(5 + u) * 64];
        }
        const unsigned* pu0 = (const unsigned*)p0b;
        const unsigned* pu1 = (const unsigned*)p1b;
        #pragma unroll
        for (int kp = 0; kp < 20; kp++) {
            half2v v2 = ash2(VBu[lane * 41 + 20 + kp]);
            half2v w2 = ash2(wo2[20 + kp]);
            half2v x0 = ash2(Uu[iq0 * 40 + 20 + kp]) + v2 + ash2(pu0[kp]);
            half2v a0 = ash2(asu2(x0) & 0x7FFF7FFFu);
            s0 = fdot2acc(x0 * c06 + a0 * c04, w2, s0);
            half2v x1 = ash2(Uu[iq1 * 40 + 20 + kp]) + v2 + ash2(pu1[kp]);
            half2v a1 = ash2(asu2(x1) & 0x7FFF7FFFu);
            s1 = fdot2acc(x1 * c06 + a1 * c04, w2, s1);
        }
    }

    // ---- masked softmax per i (exact reference semantics) ----
    float sp[2];
    #pragma unroll
    for (int q = 0; q < 2; q++) {
        float s = q ? s1 : s0;
        float mj = mask[(size_t)b * 4096 + (size_t)(iA + q) * 64 + lane];
        float sc = (s + b0) * mj;
        float m = sc;
        #pragma unroll
        for (int off = 1; off < 64; off <<= 1) m = fmaxf(m, __shfl_xor(m, off, 64));
        float e = expf(sc - m) * mj;
        float d = e;
        #pragma unroll
        for (int off = 1; off < 64; off <<= 1) d += __shfl_xor(d, off, 64);
        float p = e / (d + 1e-20f) * mj;
        PS[wave][q][lane] = p;
        float spv = p;
        #pragma unroll
        for (int off = 1; off < 64; off <<= 1) spv += __shfl_xor(spv, off, 64);
        sp[q] = spv;
    }

    // ---- message: lanes 0..39 handle k-pairs; AM2 from global (L2-hot) ----
    if (lane < 40) {
        const unsigned* pm0 = (const unsigned*)(PM3 + ((size_t)(b * 64 + iA) * 64) * 80);
        const unsigned* pm1 = pm0 + 2560;
        const unsigned* amp = AMg + gbase;
        float a00 = 0.f, a01 = 0.f, a10 = 0.f, a11 = 0.f;
        #pragma unroll 8
        for (int j = 0; j < 64; j++) {
            unsigned u0 = pm0[j * 40 + lane];
            unsigned u1 = pm1[j * 40 + lane];
            unsigned aw = amp[j * 40 + lane];
            float am0 = bflo(aw), am1 = bfhi(aw);
            float p0 = PS[wave][0][j];
            float p1 = PS[wave][1][j];
            a00 += p0 * (bflo(u0) + am0);
            a01 += p0 * (bfhi(u0) + am1);
            a10 += p1 * (bflo(u1) + am0);
            a11 += p1 * (bfhi(u1) + am1);
        }

        int k0 = 2 * lane, k1 = 2 * lane + 1;
        #pragma unroll
        for (int q = 0; q < 2; q++) {
            int i = iA + q;
            int iq = wave * 2 + q;
            unsigned aw1 = A1u[iq * 40 + lane];
            size_t orow = ((size_t)hb * 64 + i) * 80;
            float mlo = (q == 0) ? a00 : a10;
            float mhi = (q == 0) ? a01 : a11;
            float pre0 = sp[q] * bflo(aw1) + mlo + bm[k0] + ah0[orow + k0];
            float pre1 = sp[q] * bfhi(aw1) + mhi + bm[k1] + ah0[orow + k1];
            ah_next[orow + k0] = pre0 > 0.f ? pre0 : 0.f;
            ah_next[orow + k1] = pre1 > 0.f ? pre1 : 0.f;
        }
    }
}

// ---------------------------------------------------------------------------
// Merge: X[row][f] = concat(atom, ah_merged) as fp16, pitch 736, pad zeroed.
// ---------------------------------------------------------------------------
__global__ __launch_bounds__(256) void merge_kernel(
    const float* __restrict__ atom, const float* __restrict__ ah,
    _Float16* __restrict__ X)
{
    int r0 = blockIdx.x * 8;
    int t = threadIdx.x;
    for (int e = t; e < 8 * 736; e += 256) {
        int r = e / 736, f = e - r * 736;
        int row = r0 + r;
        float v;
        if (f < 82) {
            v = atom[(size_t)row * 82 + f];
        } else if (f < 722) {
            int q = f - 82, h = q / 80, k = q - h * 80;
            int b = row >> 6, i = row & 63;
            v = ah[(((size_t)(h * 32 + b)) * 64 + i) * 80 + k];
        } else {
            v = 0.f;
        }
        X[(size_t)row * 736 + f] = (_Float16)v;
    }
}

// ---------------------------------------------------------------------------
// Out GEMM via f16 MFMA. grid (128 M-tiles of 16, 2 N-tiles of 128) x 256.
// ---------------------------------------------------------------------------
__global__ __launch_bounds__(256) void out_gemm_mfma(
    const _Float16* __restrict__ X, const _Float16* __restrict__ WTo,
    const float* __restrict__ bo, float* __restrict__ out)
{
    __shared__ _Float16 Als[16 * 744];
    int bx = blockIdx.x, by = blockIdx.y;
    int t = threadIdx.x;
    int wave = t >> 6, lane = t & 63, ln = lane & 15, quad = lane >> 4;

    {
        const unsigned* src = (const unsigned*)(X + (size_t)bx * 16 * 736);
        for (int e = t; e < 16 * 368; e += 256) {
            int r = e / 368, u = e - r * 368;
            *(unsigned*)(Als + r * 744 + u * 2) = src[r * 368 + u];
        }
    }
    __syncthreads();

    int nbase = by * 128 + wave * 32;
    f32x4 acc0 = (f32x4){0.f, 0.f, 0.f, 0.f};
    f32x4 acc1 = (f32x4){0.f, 0.f, 0.f, 0.f};
    const _Float16* Bp0 = WTo + (size_t)(nbase + ln) * 736 + quad * 8;
    const _Float16* Bp1 = WTo + (size_t)(nbase + 16 + ln) * 736 + quad * 8;

    #pragma unroll
    for (int kc = 0; kc < 23; kc++) {
        half8 af = *(const half8*)(Als + ln * 744 + kc * 32 + quad * 8);
        half8 b0 = *(const half8*)(Bp0 + kc * 32);
        half8 b1 = *(const half8*)(Bp1 + kc * 32);
        acc0 = __builtin_amdgcn_mfma_f32_16x16x32_f16(af, b0, acc0, 0, 0, 0);
        acc1 = __builtin_amdgcn_mfma_f32_16x16x32_f16(af, b1, acc1, 0, 0, 0);
    }

    #pragma unroll
    for (int f = 0; f < 2; f++) {
        int c = nbase + f * 16 + ln;
        float bias = bo[c];
        f32x4 a = f ? acc1 : acc0;
        #pragma unroll
        for (int r = 0; r < 4; r++) {
            int m = quad * 4 + r;
            float v = a[r] + bias;
            out[(size_t)(bx * 16 + m) * 256 + c] = v > 0.f ? v : 0.f;
        }
    }
}

// ---------------------------------------------------------------------------
extern "C" void kernel_launch(void* const* d_in, const int* in_sizes, int n_in,
                              void* d_out, int out_size, void* d_ws, size_t ws_size,
                              hipStream_t stream)
{
    const float* atom_input = (const float*)d_in[0];
    const float* path_input = (const float*)d_in[1];
    const float* path_mask  = (const float*)d_in[2];
    const float* W_atom_i   = (const float*)d_in[3];
    const float* W_attn_h   = (const float*)d_in[4];
    const float* b_attn_h   = (const float*)d_in[5];
    const float* W_attn_o   = (const float*)d_in[6];
    const float* b_attn_o   = (const float*)d_in[7];
    const float* W_msg_h    = (const float*)d_in[8];
    const float* b_msg_h    = (const float*)d_in[9];
    const float* W_atom_o   = (const float*)d_in[10];
    const float* b_atom_o   = (const float*)d_in[11];
    float* out = (float*)d_out;

    // workspace carve-up (~67 MB)
    char* ws = (char*)d_ws;
    float*     ah0  = (float*)ws;     ws += (size_t)16384 * 80 * 4;
    float*     ah1  = (float*)ws;     ws += (size_t)16384 * 80 * 4;
    uint4v*    PT4  = (uint4v*)ws;    ws += (size_t)2048 * 640 * 16;   // 21 MB
    bf16*      PM3  = (bf16*)ws;      ws += (size_t)131072 * 80 * 2;   // 21 MB
    unsigned*  Ug   = (unsigned*)ws;  ws += (size_t)256 * 2560 * 4;
    unsigned*  Vg   = (unsigned*)ws;  ws += (size_t)256 * 2560 * 4;
    unsigned*  A1g  = (unsigned*)ws;  ws += (size_t)256 * 2560 * 4;
    unsigned*  AMg  = (unsigned*)ws;  ws += (size_t)256 * 2560 * 4;
    _Float16*  X    = (_Float16*)ws;  ws += (size_t)2048 * 736 * 2;
    bf16*      WTg  = (bf16*)ws;      ws += (size_t)2 * 80 * 128 * 2;
    bf16*      WTu  = (bf16*)ws;      ws += (size_t)4 * 80 * 96 * 2;
    bf16*      WTa  = (bf16*)ws;      ws += (size_t)8 * 80 * 96 * 2;
    _Float16*  WTo  = (_Float16*)ws;  ws += (size_t)256 * 736 * 2;
    float*     buvam= (float*)ws;     ws += (size_t)4 * 80 * 4;

    prep_kernel<<<256, 256, 0, stream>>>(W_atom_i, W_attn_h, b_attn_h, W_msg_h,
                                         W_atom_o, WTg, WTu, WTa, WTo, buvam);

    atom_proj_mfma<<<dim3(32, 8), 320, 0, stream>>>(atom_input, WTa, ah0);

    path_gemm_mfma<<<2048, 320, 0, stream>>>(path_input, WTg, PT4, PM3);

    const float* cur = ah0;
    float* nxt[2] = { ah1, ah1 };
    for (int layer = 0; layer < 2; layer++) {
        uvam_gemm_mfma<<<dim3(256, 4), 320, 0, stream>>>(
            cur, WTu, buvam, Ug, Vg, A1g, AMg);

        attn_layer_kernel<<<2048, 256, 0, stream>>>(
            Ug, Vg, A1g, AMg, PT4, PM3, path_mask, W_attn_o, b_attn_o, b_msg_h,
            ah0, nxt[layer]);
        cur = nxt[layer];
    }

    merge_kernel<<<256, 256, 0, stream>>>(atom_input, cur, X);
    out_gemm_mfma<<<dim3(128, 2), 256, 0, stream>>>(X, WTo, b_atom_o, out);
}